// Round 2
// baseline (353.887 us; speedup 1.0000x reference)
//
#include <hip/hip_runtime.h>

#define WIDTH  640
#define HEIGHT 384
#define PLANE  (WIDTH*HEIGHT)
#define STRIP  24
#define NSTRIP 16               /* 384/24 */
#define RPG    2                /* rows per group */
#define GROUPS (STRIP/RPG)      /* 12 */
#define CS_PW  696              /* padded width: pidx(649)=689 */
#define SSIM_C1 1.0e-4f
#define SSIM_C2 9.0e-4f
#define INV_N  (1.0f/23592960.0f)

// swizzle: pad every 16 slots -> breaks power-of-2 strides, keeps LDS small
__device__ __forceinline__ int pidx(int x) { return x + (x >> 4); }

__global__ void ssim_init(float* out) { out[0] = 1.0f; }

__global__ __launch_bounds__(256, 6)
void ssim_kernel(const float* __restrict__ pred, const float* __restrict__ targ,
                 float* __restrict__ out)
{
    // column sums (p, t, p*p+t*t, p*t) for RPG rows in flight
    __shared__ float4 cs4[RPG][CS_PW];
    __shared__ float  red[4];

    const int tid   = threadIdx.x;
    const int plane = blockIdx.x >> 4;       // 96 planes
    const int strip = blockIdx.x & 15;       // 16 strips of 24 rows
    const int y0s   = strip * STRIP;
    const float* __restrict__ P = pred + plane * PLANE;
    const float* __restrict__ T = targ + plane * PLANE;

    // zero the horizontal halo columns (slots [0,5) and [645,650)) for both rows
    if (tid < 20) {
        int k = tid / 10, j = tid % 10;
        int xi = (j < 5) ? j : (640 + j);
        cs4[k][pidx(xi)] = make_float4(0.f, 0.f, 0.f, 0.f);
    }

    // Bootstrap: S[c][*] = column sums for output row (y0s - 1), rows [y0s-6, y0s+4]
    float S[3][4];
#pragma unroll
    for (int c = 0; c < 3; ++c)
#pragma unroll
        for (int q = 0; q < 4; ++q) S[c][q] = 0.f;

#pragma unroll
    for (int c = 0; c < 3; ++c) {
        int x = tid + (c << 8);
        if (x < WIDTH) {
            for (int yy = y0s - 6; yy <= y0s + 4; ++yy) {
                if (yy >= 0 && yy < HEIGHT) {
                    float pv = P[yy * WIDTH + x];
                    float tv = T[yy * WIDTH + x];
                    S[c][0] += pv;
                    S[c][1] += tv;
                    S[c][2] += pv * pv + tv * tv;
                    S[c][3] += pv * tv;
                }
            }
        }
    }

    float acc = 0.f;
    const float inv121 = 1.0f / 121.0f;

    for (int g = 0; g < GROUPS; ++g) {
        const int y0 = y0s + g * RPG;

        // ---- Phase A: advance vertical sliding sums RPG rows, publish to LDS ----
#pragma unroll
        for (int c = 0; c < 3; ++c) {
            int x = tid + (c << 8);
            if (x < WIDTH) {
                int q = pidx(x + 5);
#pragma unroll
                for (int k = 0; k < RPG; ++k) {
                    int yn = y0 + k + 5;
                    int yo = y0 + k - 6;
                    float pn = (yn < HEIGHT) ? P[yn * WIDTH + x] : 0.f;
                    float tn = (yn < HEIGHT) ? T[yn * WIDTH + x] : 0.f;
                    float po = (yo >= 0)     ? P[yo * WIDTH + x] : 0.f;
                    float to = (yo >= 0)     ? T[yo * WIDTH + x] : 0.f;
                    S[c][0] += pn - po;
                    S[c][1] += tn - to;
                    S[c][2] += pn * pn + tn * tn - po * po - to * to;
                    S[c][3] += pn * tn - po * to;
                    cs4[k][q] = make_float4(S[c][0], S[c][1], S[c][2], S[c][3]);
                }
            }
        }
        __syncthreads();

        // ---- Phase B: 4 waves = 2 rows x 2 half-rows, 5 px per lane sliding ----
        {
            const int r    = tid >> 6;
            const int lane = tid & 63;
            const int row  = r & 1;
            const int base = ((r >> 1) * 320) + lane * 5;  // slots [base, base+14]

            float4 w[4];
            float4 B = make_float4(0.f, 0.f, 0.f, 0.f);
#pragma unroll
            for (int j = 0; j <= 10; ++j) {
                float4 v = cs4[row][pidx(base + j)];
                if (j < 4) w[j] = v;
                B.x += v.x; B.y += v.y; B.z += v.z; B.w += v.w;
            }
#pragma unroll
            for (int i = 0; i < 5; ++i) {
                if (i > 0) {
                    float4 n = cs4[row][pidx(base + 10 + i)];
                    B.x += n.x - w[i - 1].x;
                    B.y += n.y - w[i - 1].y;
                    B.z += n.z - w[i - 1].z;
                    B.w += n.w - w[i - 1].w;
                }
                float mp  = B.x * inv121, mt = B.y * inv121;
                float mpp = mp * mp, mtt = mt * mt, mpt = mp * mt;
                float s2  = B.z * inv121 - mpp - mtt;   // sigma_p + sigma_t
                float spt = B.w * inv121 - mpt;         // sigma_pt
                float num = (2.f * mpt + SSIM_C1) * (2.f * spt + SSIM_C2);
                float den = (mpp + mtt + SSIM_C1) * (s2 + SSIM_C2);
                acc += num / den;
            }
        }
        __syncthreads();
    }

    // ---- reduction: wave shuffle -> LDS -> one atomic per block ----
#pragma unroll
    for (int off = 32; off >= 1; off >>= 1)
        acc += __shfl_down(acc, off);
    if ((tid & 63) == 0) red[tid >> 6] = acc;
    __syncthreads();
    if (tid == 0) {
        float s = red[0] + red[1] + red[2] + red[3];
        atomicAdd(out, -s * INV_N);
    }
}

extern "C" void kernel_launch(void* const* d_in, const int* in_sizes, int n_in,
                              void* d_out, int out_size, void* d_ws, size_t ws_size,
                              hipStream_t stream) {
    const float* pred = (const float*)d_in[0];
    const float* targ = (const float*)d_in[1];
    float* out = (float*)d_out;
    ssim_init<<<1, 1, 0, stream>>>(out);
    ssim_kernel<<<96 * NSTRIP, 256, 0, stream>>>(pred, targ, out);
}

// Round 3
// 280.461 us; speedup vs baseline: 1.2618x; 1.2618x over previous
//
#include <hip/hip_runtime.h>
#include <hip/hip_fp16.h>

#define WIDTH   640
#define HEIGHT  384
#define PLANE   (WIDTH*HEIGHT)
#define STRIP_H 48
#define NSTRIP  8                 /* 384/48 */
#define GROUPS  24                /* STRIP_H/2 */
#define NBLK    (96*NSTRIP)       /* 768 = 3 blocks/CU exactly */
#define CS_W    656               /* slots 0..649 used, slot = x+5 */
#define SSIM_C1 1.0e-4f
#define SSIM_C2 9.0e-4f
#define INV_N   (1.0f/23592960.0f)

__device__ __forceinline__ __half2 packh2(float a, float b) {
    return __float22half2_rn(make_float2(a, b));
}

__global__ __launch_bounds__(256, 3)
void ssim_main(const float* __restrict__ pred, const float* __restrict__ targ,
               float* __restrict__ ws)
{
    __shared__ __half2 ring[11][WIDTH]; // raw (p,t) fp16 pairs, 11-row history
    __shared__ __half2 csA[2][CS_W];    // column sums (Sp, St), slot = x+5
    __shared__ __half2 csB[2][CS_W];    // column sums (Spp+Stt, Spt)
    __shared__ float red[4];

    const int tid   = threadIdx.x;
    const int plane = blockIdx.x % 96;      // neighbors-in-strip differ by 96 = same XCD
    const int strip = blockIdx.x / 96;      // 0..7
    const int y0s   = strip * STRIP_H;
    const float* __restrict__ P = pred + plane * PLANE;
    const float* __restrict__ T = targ + plane * PLANE;

    const __half2 hz = packh2(0.f, 0.f);

    // zero horizontal-halo cs slots (stay zero forever)
    if (tid < 20) {
        int k = tid / 10, j = tid % 10;
        int s = (j < 5) ? j : (640 + j);    // {0..4, 645..649}
        csA[k][s] = hz; csB[k][s] = hz;
    }

    // ---- Bootstrap: stage rows [y0s-6, y0s+4] into ring slots 0..10 and build
    //      column sums for output row y0s-1 (all arithmetic on quantized values)
    float S[3][4];
#pragma unroll
    for (int c = 0; c < 3; ++c) { S[c][0]=S[c][1]=S[c][2]=S[c][3]=0.f; }

#pragma unroll
    for (int c = 0; c < 3; ++c) {
        int x = tid + (c << 8);
        if (x < WIDTH) {
            for (int j = 0; j < 11; ++j) {
                int yy = y0s - 6 + j;                       // always < HEIGHT
                __half2 h = (yy >= 0) ? packh2(P[yy*WIDTH+x], T[yy*WIDTH+x]) : hz;
                ring[j][x] = h;
                float2 v = __half22float2(h);
                S[c][0] += v.x;  S[c][1] += v.y;
                S[c][2] += v.x*v.x + v.y*v.y;
                S[c][3] += v.x*v.y;
            }
        }
    }

    float acc = 0.f;
    const float inv121 = 1.0f / 121.0f;
    int rs = 0;   // ring slot of the row leaving/entering at k=0 of this group

    for (int g = 0; g < GROUPS; ++g) {
        const int y0 = y0s + (g << 1);

        // ---- Phase A: advance 2 rows; subtract old from LDS ring, add new from HBM
#pragma unroll
        for (int c = 0; c < 3; ++c) {
            int x = tid + (c << 8);
            if (x < WIDTH) {
#pragma unroll
                for (int k = 0; k < 2; ++k) {
                    int slot = rs + k; if (slot >= 11) slot -= 11;
                    int yn = y0 + k + 5;
                    __half2 hn = (yn < HEIGHT) ? packh2(P[yn*WIDTH+x], T[yn*WIDTH+x]) : hz;
                    __half2 ho = ring[slot][x];
                    ring[slot][x] = hn;
                    float2 n = __half22float2(hn);
                    float2 o = __half22float2(ho);
                    S[c][0] += n.x - o.x;
                    S[c][1] += n.y - o.y;
                    S[c][2] += n.x*n.x + n.y*n.y - o.x*o.x - o.y*o.y;
                    S[c][3] += n.x*n.y - o.x*o.y;
                    csA[k][x+5] = packh2(S[c][0], S[c][1]);
                    csB[k][x+5] = packh2(S[c][2], S[c][3]);
                }
            }
        }
        __syncthreads();

        // ---- Phase B: 4 waves = 2 rows x 2 halves; 5 px/lane; stride-5 = conflict-free
        {
            const int r    = tid >> 6;
            const int lane = tid & 63;
            const int k    = r & 1;
            const int base = ((r >> 1) * 320) + lane * 5;   // slots [base, base+14]

            __half2 a[15], b[15];
#pragma unroll
            for (int j = 0; j < 15; ++j) { a[j] = csA[k][base+j]; b[j] = csB[k][base+j]; }

            float B0 = 0.f, B1 = 0.f, B2 = 0.f, B3 = 0.f;
#pragma unroll
            for (int j = 0; j <= 10; ++j) {
                float2 u = __half22float2(a[j]);
                float2 v = __half22float2(b[j]);
                B0 += u.x; B1 += u.y; B2 += v.x; B3 += v.y;
            }
#pragma unroll
            for (int i = 0; i < 5; ++i) {
                if (i > 0) {
                    float2 un = __half22float2(a[10+i]);
                    float2 vn = __half22float2(b[10+i]);
                    float2 uo = __half22float2(a[i-1]);
                    float2 vo = __half22float2(b[i-1]);
                    B0 += un.x - uo.x; B1 += un.y - uo.y;
                    B2 += vn.x - vo.x; B3 += vn.y - vo.y;
                }
                float mp  = B0 * inv121, mt = B1 * inv121;
                float mpp = mp*mp, mtt = mt*mt, mpt = mp*mt;
                float s2  = B2 * inv121 - mpp - mtt;   // sigma_p + sigma_t
                float spt = B3 * inv121 - mpt;         // sigma_pt
                float num = (2.f*mpt + SSIM_C1) * (2.f*spt + SSIM_C2);
                float den = (mpp + mtt + SSIM_C1) * (s2 + SSIM_C2);
                acc += num / den;
            }
        }
        __syncthreads();

        rs += 2; if (rs >= 11) rs -= 11;
    }

    // ---- block reduction -> one plain store per block (no atomics)
#pragma unroll
    for (int off = 32; off >= 1; off >>= 1)
        acc += __shfl_down(acc, off);
    if ((tid & 63) == 0) red[tid >> 6] = acc;
    __syncthreads();
    if (tid == 0)
        ws[blockIdx.x] = red[0] + red[1] + red[2] + red[3];
}

__global__ void ssim_reduce(const float* __restrict__ ws, float* __restrict__ out)
{
    __shared__ float red[4];
    const int tid = threadIdx.x;
    float s = ws[tid] + ws[tid + 256] + ws[tid + 512];
#pragma unroll
    for (int off = 32; off >= 1; off >>= 1)
        s += __shfl_down(s, off);
    if ((tid & 63) == 0) red[tid >> 6] = s;
    __syncthreads();
    if (tid == 0)
        out[0] = 1.0f - (red[0] + red[1] + red[2] + red[3]) * INV_N;
}

extern "C" void kernel_launch(void* const* d_in, const int* in_sizes, int n_in,
                              void* d_out, int out_size, void* d_ws, size_t ws_size,
                              hipStream_t stream) {
    const float* pred = (const float*)d_in[0];
    const float* targ = (const float*)d_in[1];
    float* out = (float*)d_out;
    float* ws  = (float*)d_ws;          // 768 floats of partial sums
    ssim_main<<<NBLK, 256, 0, stream>>>(pred, targ, ws);
    ssim_reduce<<<1, 256, 0, stream>>>(ws, out);
}

// Round 5
// 245.026 us; speedup vs baseline: 1.4443x; 1.1446x over previous
//
#include <hip/hip_runtime.h>
#include <hip/hip_fp16.h>

#define WIDTH   640
#define HEIGHT  384
#define PLANE   (WIDTH*HEIGHT)
#define STRIP_H 48
#define NSTRIP  8                 /* 384/48 */
#define GROUPS  24                /* STRIP_H/2 */
#define NBLK    (96*NSTRIP)       /* 768 = 3 blocks/CU exactly */
#define CS_W    656               /* slots 0..649 used, slot = x+5 */
#define SSIM_C1 1.0e-4f
#define SSIM_C2 9.0e-4f
#define INV_N   (1.0f/23592960.0f)

__device__ __forceinline__ __half2 packh2(float a, float b) {
    // single v_cvt_pkrtz_f16_f32; rtz quantization is consistent add/sub so no drift
    __fp16 __attribute__((ext_vector_type(2))) v = __builtin_amdgcn_cvt_pkrtz(a, b);
    __half2 r;
    __builtin_memcpy(&r, &v, sizeof(r));
    return r;
}

__global__ __launch_bounds__(256, 3)
void ssim_main(const float* __restrict__ pred, const float* __restrict__ targ,
               float* __restrict__ ws)
{
    __shared__ __half2 ring[11][WIDTH];   // raw (p,t) fp16 pairs, 11-row history (28.2 KB)
    __shared__ float4  cs[2][CS_W];       // column sums (Sp, St, Spp+Stt, Spt)  (21 KB)
    __shared__ float   red[4];

    const int tid   = threadIdx.x;
    const int plane = blockIdx.x % 96;      // vertical neighbors differ by 96 -> same XCD
    const int strip = blockIdx.x / 96;      // 0..7
    const int y0s   = strip * STRIP_H;
    const float* __restrict__ P = pred + plane * PLANE;
    const float* __restrict__ T = targ + plane * PLANE;

    // zero horizontal-halo cs slots once (Phase A never touches them; first
    // Phase-B read is after the first barrier, which orders this write)
    if (tid < 20) {
        int k = tid / 10, j = tid % 10;
        int s = (j < 5) ? j : (640 + j);    // {0..4, 645..649}
        cs[k][s] = make_float4(0.f, 0.f, 0.f, 0.f);
    }

    // ---- Bootstrap: stage rows [y0s-6, y0s+4] into ring, build column sums
    //      for output row y0s-1 (all arithmetic on the quantized fp16 values)
    float S[3][4];
#pragma unroll
    for (int c = 0; c < 3; ++c) { S[c][0]=S[c][1]=S[c][2]=S[c][3]=0.f; }

#pragma unroll
    for (int c = 0; c < 3; ++c) {
        int x = tid + (c << 8);
        if (x < WIDTH) {
            for (int j = 0; j < 11; ++j) {
                int yy = y0s - 6 + j;
                __half2 h = (yy >= 0) ? packh2(P[yy*WIDTH+x], T[yy*WIDTH+x])
                                      : packh2(0.f, 0.f);
                ring[j][x] = h;
                float2 v = __half22float2(h);
                S[c][0] += v.x;  S[c][1] += v.y;
                S[c][2] += v.x*v.x + v.y*v.y;
                S[c][3] += v.x*v.y;
            }
        }
    }

    // prefetch registers for the two rows entering the window each group
    float pfP[3][2], pfT[3][2];
    auto do_prefetch = [&](int gg) {
        const int y0 = y0s + (gg << 1);
#pragma unroll
        for (int c = 0; c < 3; ++c) {
            int x = tid + (c << 8);
            if (x < WIDTH) {
#pragma unroll
                for (int k = 0; k < 2; ++k) {
                    int yn = y0 + k + 5;
                    bool v = (yn < HEIGHT);
                    pfP[c][k] = v ? P[yn*WIDTH + x] : 0.f;
                    pfT[c][k] = v ? T[yn*WIDTH + x] : 0.f;
                }
            }
        }
    };
    do_prefetch(0);

    float acc = 0.f;
    const float inv121 = 1.0f / 121.0f;
    int rs = 0;   // ring slot of the row leaving/entering at k=0 of this group

    for (int g = 0; g < GROUPS; ++g) {
        // consume this group's prefetched rows, then immediately issue next
        // group's loads -> VMEM latency overlaps rest of A + barrier + B
        float cP[3][2], cT[3][2];
#pragma unroll
        for (int c = 0; c < 3; ++c)
#pragma unroll
            for (int k = 0; k < 2; ++k) { cP[c][k] = pfP[c][k]; cT[c][k] = pfT[c][k]; }

        if (g + 1 < GROUPS) do_prefetch(g + 1);

        // ---- Phase A: advance 2 rows; subtract old from LDS ring, add new
#pragma unroll
        for (int c = 0; c < 3; ++c) {
            int x = tid + (c << 8);
            if (x < WIDTH) {
#pragma unroll
                for (int k = 0; k < 2; ++k) {
                    int slot = rs + k; if (slot >= 11) slot -= 11;
                    float nx = cP[c][k], ny = cT[c][k];
                    __half2 hn = packh2(nx, ny);
                    __half2 ho = ring[slot][x];
                    ring[slot][x] = hn;
                    float2 nq = __half22float2(hn);   // use quantized value
                    float2 o  = __half22float2(ho);
                    S[c][0] += nq.x - o.x;
                    S[c][1] += nq.y - o.y;
                    S[c][2] += nq.x*nq.x + nq.y*nq.y - o.x*o.x - o.y*o.y;
                    S[c][3] += nq.x*nq.y - o.x*o.y;
                    cs[k][x + 5] = make_float4(S[c][0], S[c][1], S[c][2], S[c][3]);
                }
            }
        }
        __syncthreads();

        // ---- Phase B: 4 waves = 2 rows x 2 halves; 5 px/lane; b128 reads,
        //      lane stride 20 dwords -> minimum bank aliasing (conflict-free)
        {
            const int r    = tid >> 6;
            const int lane = tid & 63;
            const int k    = r & 1;
            const int base = ((r >> 1) * 320) + lane * 5;   // slots [base, base+14]

            float4 w[4];
            float4 B = make_float4(0.f, 0.f, 0.f, 0.f);
#pragma unroll
            for (int j = 0; j <= 10; ++j) {
                float4 v = cs[k][base + j];
                if (j < 4) w[j] = v;
                B.x += v.x; B.y += v.y; B.z += v.z; B.w += v.w;
            }
#pragma unroll
            for (int i = 0; i < 5; ++i) {
                if (i > 0) {
                    float4 n = cs[k][base + 10 + i];
                    B.x += n.x - w[i-1].x;
                    B.y += n.y - w[i-1].y;
                    B.z += n.z - w[i-1].z;
                    B.w += n.w - w[i-1].w;
                }
                float mp  = B.x * inv121, mt = B.y * inv121;
                float mpp = mp*mp, mtt = mt*mt, mpt = mp*mt;
                float s2  = B.z * inv121 - mpp - mtt;   // sigma_p + sigma_t
                float spt = B.w * inv121 - mpt;         // sigma_pt
                float num = (2.f*mpt + SSIM_C1) * (2.f*spt + SSIM_C2);
                float den = (mpp + mtt + SSIM_C1) * (s2 + SSIM_C2);
                acc += num * __builtin_amdgcn_rcpf(den);
            }
        }
        __syncthreads();

        rs += 2; if (rs >= 11) rs -= 11;
    }

    // ---- block reduction -> one plain store per block (no atomics)
#pragma unroll
    for (int off = 32; off >= 1; off >>= 1)
        acc += __shfl_down(acc, off);
    if ((tid & 63) == 0) red[tid >> 6] = acc;
    __syncthreads();
    if (tid == 0)
        ws[blockIdx.x] = red[0] + red[1] + red[2] + red[3];
}

__global__ void ssim_reduce(const float* __restrict__ ws, float* __restrict__ out)
{
    __shared__ float red[4];
    const int tid = threadIdx.x;
    float s = ws[tid] + ws[tid + 256] + ws[tid + 512];
#pragma unroll
    for (int off = 32; off >= 1; off >>= 1)
        s += __shfl_down(s, off);
    if ((tid & 63) == 0) red[tid >> 6] = s;
    __syncthreads();
    if (tid == 0)
        out[0] = 1.0f - (red[0] + red[1] + red[2] + red[3]) * INV_N;
}

extern "C" void kernel_launch(void* const* d_in, const int* in_sizes, int n_in,
                              void* d_out, int out_size, void* d_ws, size_t ws_size,
                              hipStream_t stream) {
    const float* pred = (const float*)d_in[0];
    const float* targ = (const float*)d_in[1];
    float* out = (float*)d_out;
    float* ws  = (float*)d_ws;          // 768 floats of partial sums
    ssim_main<<<NBLK, 256, 0, stream>>>(pred, targ, ws);
    ssim_reduce<<<1, 256, 0, stream>>>(ws, out);
}